// Round 17
// baseline (3762.006 us; speedup 1.0000x reference)
//
#include <hip/hip_runtime.h>
#include <hip/hip_bf16.h>
#include <math.h>

// WaveNet forward on gfx950 — round 17: r16 base (best: 3546us) +
// (a) gau6 3-deep register staging pipeline (loads issued 3 super-steps
// ahead, ~2.5 MFMA phases of latency cover), (b) skipres6 weight-load
// hoist before the z-stage barrier.

#define T_IN 18308
#define T_OUT 16262

typedef unsigned short u16;
typedef unsigned int u32;
typedef __attribute__((ext_vector_type(8))) short short8_t;
typedef __attribute__((ext_vector_type(4))) float f32x4;

__device__ __forceinline__ float bf2f(u16 h) { return __uint_as_float(((u32)h) << 16); }
__device__ __forceinline__ u16 f2bf(float f) {
  u32 u = __float_as_uint(f);
  return (u16)((u + 0x7fffu + ((u >> 16) & 1u)) >> 16);
}

// ---- MFMA fragment packing ----
// Frag layout per (mt,ks): dst[(mt*nks+ks)*512 + lane*8 + j] = W[mt*16+(lane&15)][ks*32+(lane>>4)*8+j]
__global__ void k_pack_frag(const float* __restrict__ src, u16* __restrict__ dst,
                            int M, int K, int L, long src_lstride) {
  int nks = K >> 5;
  long per = (long)M * K;
  long total = per * L;
  for (long idx = blockIdx.x * (long)blockDim.x + threadIdx.x; idx < total; idx += (long)gridDim.x * blockDim.x) {
    int l = (int)(idx / per); long r = idx - (long)l * per;
    int j = (int)(r & 7); int lane = (int)((r >> 3) & 63); int fid = (int)(r >> 9);
    int ks = fid % nks; int mt = fid / nks;
    int row = mt * 16 + (lane & 15);
    int col = ks * 32 + ((lane >> 4) << 3) + j;
    dst[idx] = f2bf(src[l * src_lstride + (long)row * K + col]);
  }
}

// GAU fused weights: logical W[l][256][896]: k<384 tap0, k<768 tap1, else psig(lc chans 0..127)
__global__ void k_pack_frag_gau(const float* __restrict__ sig_w, const float* __restrict__ gate_w,
                                const float* __restrict__ psig_w, const float* __restrict__ pgate_w,
                                u16* __restrict__ dstF, u16* __restrict__ dstG) {
  const long per = 229376; // 16mt * 28ks * 512
  long total = per * 20;
  for (long idx = blockIdx.x * (long)blockDim.x + threadIdx.x; idx < total; idx += (long)gridDim.x * blockDim.x) {
    int l = (int)(idx / per); long r = idx - (long)l * per;
    int j = (int)(r & 7); int lane = (int)((r >> 3) & 63); int fid = (int)(r >> 9);
    int ks = fid % 28; int mt = fid / 28;
    int row = mt * 16 + (lane & 15);
    int k = ks * 32 + ((lane >> 4) << 3) + j;
    float vF, vG;
    if (k < 384) {
      vF = sig_w[(((long)l * 256 + row) * 384 + k) * 2 + 0];
      vG = gate_w[(((long)l * 256 + row) * 384 + k) * 2 + 0];
    } else if (k < 768) {
      vF = sig_w[(((long)l * 256 + row) * 384 + (k - 384)) * 2 + 1];
      vG = gate_w[(((long)l * 256 + row) * 384 + (k - 384)) * 2 + 1];
    } else {
      vF = psig_w[((long)l * 256 + row) * 256 + (k - 768)];
      vG = pgate_w[((long)l * 256 + row) * 256 + (k - 768)];
    }
    dstF[idx] = f2bf(vF);
    dstG[idx] = f2bf(vG);
  }
}

// tconv per-phase weight pack (f32, stages 1-3): dst[p][i*nk+m][o] = w[i][o][K-1-(S-1-p)-m*S]
__global__ void k_pack_tconv(const float* __restrict__ w, float* __restrict__ dst,
                             int S, int K, int nk) {
  int Ktot = 128 * nk;
  long total = (long)S * Ktot * 128;
  for (long idx = blockIdx.x * (long)blockDim.x + threadIdx.x; idx < total; idx += (long)gridDim.x * blockDim.x) {
    int o = (int)(idx & 127);
    long tmp = idx >> 7;
    int k = (int)(tmp % Ktot);
    int p = (int)(tmp / Ktot);
    int i = k / nk, m = k % nk;
    dst[idx] = w[((long)i * 128 + o) * K + (K - 1 - (S - 1 - p) - m * S)];
  }
}

// stage-4 tconv weights, fragment-packed per phase: M=128, K=512 (k = i*4+m), S=4, KW=16
__global__ void k_pack_tc4f(const float* __restrict__ w, u16* __restrict__ dst) {
  const long perp = 65536; // 8mt * 16ks * 512
  long total = perp * 4;
  for (long idx = blockIdx.x * (long)blockDim.x + threadIdx.x; idx < total; idx += (long)gridDim.x * blockDim.x) {
    int p = (int)(idx / perp); long r = idx - (long)p * perp;
    int j = (int)(r & 7); int lane = (int)((r >> 3) & 63); int fid = (int)(r >> 9);
    int ks = fid & 15; int mt = fid >> 4;
    int o = mt * 16 + (lane & 15);
    int k = ks * 32 + ((lane >> 4) << 3) + j;
    int i = k >> 2, m = k & 3;
    dst[idx] = f2bf(w[((long)i * 128 + o) * 16 + (12 + p - 4 * m)]);
  }
}

// im2col for stage-4 tconv input: dst[b][j][i*4+m] = lcs3[b][i][j+m]  (bf16)
__global__ void k_im2col3(const float* __restrict__ lcs3, u16* __restrict__ dst) {
  long total = 4L * 4580 * 512;
  for (long idx = blockIdx.x * (long)blockDim.x + threadIdx.x; idx < total; idx += (long)gridDim.x * blockDim.x) {
    int col = (int)(idx & 511);
    long t2 = idx >> 9;
    int jj = (int)(t2 % 4580);
    int b = (int)(t2 / 4580);
    int i = col >> 2, m = col & 3;
    float v = (jj + m < 4580) ? lcs3[((long)b * 128 + i) * 4580 + jj + m] : 0.0f;
    dst[idx] = f2bf(v);
  }
}

__global__ void k_gc(const float* __restrict__ emb_w, const float* __restrict__ emb_b,
                     const int* __restrict__ spk, float* __restrict__ gc) {
  int i = threadIdx.x + blockIdx.x * blockDim.x;
  if (i < 512) { int b = i / 128, g = i % 128; gc[b * 128 + g] = emb_w[g * 40 + spk[b]] + emb_b[g]; }
}

__global__ void k_cbias(const float* __restrict__ psig_w, const float* __restrict__ pgate_w,
                        const float* __restrict__ sig_b, const float* __restrict__ gate_b,
                        const float* __restrict__ gc, float* __restrict__ cbias) {
  int l = blockIdx.x; int fg = blockIdx.y >> 2; int b = blockIdx.y & 3; int c = threadIdx.x;
  const float* p = fg ? pgate_w : psig_w;
  const float* bb = fg ? gate_b : sig_b;
  float acc = bb[l * 256 + c];
  const float* prow = p + ((long)(l * 256 + c)) * 256 + 128;
  const float* g = gc + b * 128;
  for (int k = 0; k < 128; ++k) acc += prow[k] * g[k];
  cbias[((l * 2 + fg) * 4 + b) * 256 + c] = acc;
}

// jitter-gather + conv3 (VALID): out (B,128,62) f32 ch-major, stride 64
__global__ void k_lc0(const float* __restrict__ lc_sparse, const int* __restrict__ jit,
                      const float* __restrict__ w, const float* __restrict__ bias, float* __restrict__ out) {
  int b = blockIdx.x; int t = blockIdx.y; int co = threadIdx.x; // 128
  __shared__ float xs[64][3];
  for (int i = threadIdx.x; i < 192; i += blockDim.x) {
    int ci = i / 3, kk = i % 3;
    xs[ci][kk] = lc_sparse[((long)b * 64 + ci) * 64 + jit[b * 64 + t + kk]];
  }
  __syncthreads();
  float acc = bias[co];
  #pragma unroll 8
  for (int ci = 0; ci < 64; ++ci) {
    const float* wr = w + ((long)co * 64 + ci) * 3;
    acc += wr[0] * xs[ci][0] + wr[1] * xs[ci][1] + wr[2] * xs[ci][2];
  }
  out[((long)b * 128 + co) * 64 + t] = acc;
}

// Transposed conv stages 1-3 (f32 tiled GEMM, small) — out f32 ch-major
template<int NK>
__global__ __launch_bounds__(256) void k_tconvg(
    const float* __restrict__ xin, int Lin, int xstride,
    float* __restrict__ yout, int Lout, int ostride,
    const float* __restrict__ wp, const float* __restrict__ bias, int S) {
  const int Ktot = 128 * NK;
  __shared__ __align__(16) float Ws[32][64];
  __shared__ __align__(16) float Xs[32][64];
  int b = blockIdx.z;
  int p = blockIdx.y >> 1, bm0 = (blockIdx.y & 1) * 64;
  int j0 = blockIdx.x * 64;
  int tid = threadIdx.x, tn = tid & 15, tm = tid >> 4;
  float acc[4][4] = {};
  int kchunks = Ktot / 32;
  for (int kc = 0; kc < kchunks; ++kc) {
    int k0 = kc * 32;
    {
      int kk = tid >> 3, m8 = (tid & 7) * 8;
      const float* src = wp + ((long)p * Ktot + k0 + kk) * 128 + bm0 + m8;
      float4 f1 = *(const float4*)src;
      float4 f2 = *(const float4*)(src + 4);
      Ws[kk][m8 + 0] = f1.x; Ws[kk][m8 + 1] = f1.y; Ws[kk][m8 + 2] = f1.z; Ws[kk][m8 + 3] = f1.w;
      Ws[kk][m8 + 4] = f2.x; Ws[kk][m8 + 5] = f2.y; Ws[kk][m8 + 6] = f2.z; Ws[kk][m8 + 7] = f2.w;
    }
    #pragma unroll
    for (int rr = 0; rr < 8; ++rr) {
      int kk = rr * 4 + (tid >> 6), tt = tid & 63;
      int k = k0 + kk;
      int i = k / NK, m = k % NK;
      int j = j0 + tt;
      Xs[kk][tt] = (j + m < Lin) ? xin[((long)(b * 128 + i)) * xstride + j + m] : 0.0f;
    }
    __syncthreads();
    #pragma unroll 8
    for (int kk = 0; kk < 32; ++kk) {
      float av[4], bv[4];
      #pragma unroll
      for (int i = 0; i < 4; ++i) av[i] = Ws[kk][tm * 4 + i];
      #pragma unroll
      for (int j = 0; j < 4; ++j) bv[j] = Xs[kk][tn * 4 + j];
      #pragma unroll
      for (int i = 0; i < 4; ++i)
        #pragma unroll
        for (int j = 0; j < 4; ++j) acc[i][j] = fmaf(av[i], bv[j], acc[i][j]);
    }
    __syncthreads();
  }
  #pragma unroll
  for (int jj = 0; jj < 4; ++jj) {
    int j = j0 + tn * 4 + jj;
    int t = j * S + p;
    if (t >= Lout) continue;
    #pragma unroll
    for (int i = 0; i < 4; ++i) {
      int o = bm0 + tm * 4 + i;
      yout[((long)b * 128 + o) * ostride + t] = acc[i][jj] + bias[o];
    }
  }
}

// stage-4 tconv via MFMA: B = im2col [b][j][512], per-phase packed W, out lcbf [b][t=4j+p][128]
__global__ __launch_bounds__(256) void k_tconv4m(
    const u16* __restrict__ im, const u16* __restrict__ Wp4,
    const float* __restrict__ bias, u16* __restrict__ out) {
  int lane = threadIdx.x & 63, wave = threadIdx.x >> 6;
  int b = blockIdx.z;
  int p = blockIdx.y >> 1, chb = (blockIdx.y & 1) << 6;
  int tbase = (blockIdx.x << 8) + (wave << 6);
  int lrow = lane & 15, lk = (lane >> 4) << 3;
  int mt0 = chb >> 4;
  const u16* Wp = Wp4 + (long)p * 65536;
  f32x4 zed = {0.f, 0.f, 0.f, 0.f};
  f32x4 acc[4][4];
  #pragma unroll
  for (int m = 0; m < 4; ++m)
    #pragma unroll
    for (int n = 0; n < 4; ++n) acc[m][n] = zed;
  const u16* ib = im + (long)b * 4580 * 512;
  for (int ks = 0; ks < 16; ++ks) {
    short8_t a[4];
    #pragma unroll
    for (int m = 0; m < 4; ++m)
      a[m] = *(const short8_t*)(Wp + ((long)((mt0 + m) * 16 + ks) << 9) + (lane << 3));
    #pragma unroll
    for (int n = 0; n < 4; ++n) {
      int j = tbase + (n << 4) + lrow;
      j = min(j, 4579);
      short8_t bv = *(const short8_t*)(ib + (long)j * 512 + (ks << 5) + lk);
      #pragma unroll
      for (int m = 0; m < 4; ++m)
        acc[m][n] = __builtin_amdgcn_mfma_f32_16x16x32_bf16(a[m], bv, acc[m][n], 0, 0, 0);
    }
  }
  #pragma unroll
  for (int n = 0; n < 4; ++n) {
    int j = tbase + (n << 4) + lrow;
    int t = j * 4 + p;
    if (t >= T_IN) continue;
    #pragma unroll
    for (int m = 0; m < 4; ++m) {
      int ch0 = chb + (m << 4) + ((lane >> 4) << 2);
      f32x4 bb = *(const f32x4*)(bias + ch0);
      ushort4 o;
      o.x = f2bf(acc[m][n][0] + bb[0]);
      o.y = f2bf(acc[m][n][1] + bb[1]);
      o.z = f2bf(acc[m][n][2] + bb[2]);
      o.w = f2bf(acc[m][n][3] + bb[3]);
      *(ushort4*)(out + ((long)b * T_IN + t) * 128 + ch0) = o;
    }
  }
}

// wav transpose: f32 ch-major [b][256][T] -> bf16 t-major [b][T][256]
__global__ __launch_bounds__(256) void k_wav_t(const float* __restrict__ wav, u16* __restrict__ dst) {
  __shared__ float xs[32][65];
  int b = blockIdx.z, c0 = blockIdx.y * 32, t0 = blockIdx.x * 64;
  int tid = threadIdx.x;
  #pragma unroll
  for (int i = 0; i < 8; ++i) {
    int idx = tid + i * 256;
    int c = idx >> 6, tl = idx & 63;
    int t = t0 + tl; if (t >= T_IN) t = T_IN - 1;
    xs[c][tl] = wav[((long)b * 256 + c0 + c) * T_IN + t];
  }
  __syncthreads();
  #pragma unroll
  for (int i = 0; i < 8; ++i) {
    int idx = tid + i * 256;
    int tl = idx >> 5, c = idx & 31;
    int t = t0 + tl;
    if (t < T_IN) dst[((long)b * T_IN + t) * 256 + c0 + c] = f2bf(xs[c][tl]);
  }
}

// base 1x1 conv MFMA: M=384, K=256, B = wavT, out xA bf16 t-major [b][t][384]
__global__ __launch_bounds__(256) void k_basem(
    const u16* __restrict__ wavT, const u16* __restrict__ Wp,
    const float* __restrict__ bias, u16* __restrict__ X) {
  int lane = threadIdx.x & 63, wave = threadIdx.x >> 6;
  int b = blockIdx.z, chb = blockIdx.y << 6;
  int tbase = (blockIdx.x << 8) + (wave << 6);
  int lrow = lane & 15, lk = (lane >> 4) << 3;
  int mt0 = chb >> 4;
  f32x4 zed = {0.f, 0.f, 0.f, 0.f};
  f32x4 acc[4][4];
  #pragma unroll
  for (int m = 0; m < 4; ++m)
    #pragma unroll
    for (int n = 0; n < 4; ++n) acc[m][n] = zed;
  const u16* xb = wavT + (long)b * T_IN * 256;
  for (int ks = 0; ks < 8; ++ks) {
    short8_t a[4];
    #pragma unroll
    for (int m = 0; m < 4; ++m)
      a[m] = *(const short8_t*)(Wp + ((long)((mt0 + m) * 8 + ks) << 9) + (lane << 3));
    #pragma unroll
    for (int n = 0; n < 4; ++n) {
      int row = tbase + (n << 4) + lrow;
      row = min(row, T_IN - 1);
      short8_t bv = *(const short8_t*)(xb + (long)row * 256 + (ks << 5) + lk);
      #pragma unroll
      for (int m = 0; m < 4; ++m)
        acc[m][n] = __builtin_amdgcn_mfma_f32_16x16x32_bf16(a[m], bv, acc[m][n], 0, 0, 0);
    }
  }
  #pragma unroll
  for (int n = 0; n < 4; ++n) {
    int t = tbase + (n << 4) + lrow;
    if (t >= T_IN) continue;
    #pragma unroll
    for (int m = 0; m < 4; ++m) {
      int ch0 = chb + (m << 4) + ((lane >> 4) << 2);
      f32x4 bb = *(const f32x4*)(bias + ch0);
      ushort4 o;
      o.x = f2bf(acc[m][n][0] + bb[0]);
      o.y = f2bf(acc[m][n][1] + bb[1]);
      o.z = f2bf(acc[m][n][2] + bb[2]);
      o.w = f2bf(acc[m][n][3] + bb[3]);
      *(ushort4*)(X + ((long)b * T_IN + t) * 384 + ch0) = o;
    }
  }
}

// ---- GAU v6q: 4-wave blocks, T=64, KU=4 (7 barriers), 3-deep reg pipeline ----
// Loads for super-step ss+3 issued at top of step ss; step ss+1's regs
// (loaded at step ss-2) written at bottom of step ss -> ~2.5 phases cover.
__global__ __launch_bounds__(256, 3) void k_gau6(
    const u16* __restrict__ Xc, const u16* __restrict__ Lc,
    const u16* __restrict__ WpF, const u16* __restrict__ WpG,
    const float* __restrict__ cb, u16* __restrict__ Z,
    int Lz, int d, int cl, int nt) {
  __shared__ __align__(16) u16 stg[2][8192];
  int lane = threadIdx.x & 63, wave = threadIdx.x >> 6;
  int bx = blockIdx.x;
  int tb = ((bx >> 4) << 3) + (bx & 7);
  int chh = (bx >> 3) & 1;
  if (tb >= nt) return;
  int tbase = tb << 6;
  int b = blockIdx.z;
  int chb = (chh << 7) + (wave << 5);
  int mt0 = chb >> 4;
  int lrow = lane & 15, lk16 = lane >> 4;
  const u16* xb = Xc + (long)b * T_IN * 384;
  const u16* lb = Lc + (long)b * T_IN * 128;
  const u16* pWF0 = WpF + (((long)mt0 * 28) << 9) + (lane << 3);
  const u16* pWF1 = WpF + (((long)(mt0 + 1) * 28) << 9) + (lane << 3);
  const u16* pWG0 = WpG + (((long)mt0 * 28) << 9) + (lane << 3);
  const u16* pWG1 = WpG + (((long)(mt0 + 1) * 28) << 9) + (lane << 3);
  int r0 = tbase + (wave << 4) + lrow;
  const u16* s0 = xb + (long)min(r0, T_IN - 1) * 384 + (lk16 << 3);
  const u16* s1 = xb + (long)min(r0 + d, T_IN - 1) * 384 + (lk16 << 3);
  const u16* s2 = lb + (long)min(r0 + cl, T_IN - 1) * 128 + (lk16 << 3);
  u16* wd = &stg[0][0] + (wave << 9) + (lane << 3);
  // compile-time segmented load pointer for k-substep kn
  #define LDP(kn) ((kn) < 12 ? (s0 + ((kn) << 5)) : (kn) < 24 ? (s1 + (((kn) - 12) << 5)) : (s2 + (((kn) - 24) << 5)))

  f32x4 zed = {0.f, 0.f, 0.f, 0.f};
  f32x4 accF[2][4], accG[2][4];
  #pragma unroll
  for (int m = 0; m < 2; ++m)
    #pragma unroll
    for (int n = 0; n < 4; ++n) { accF[m][n] = zed; accG[m][n] = zed; }

  // prologue: stage step0 into buf0; issue step-1 (rA) and step-2 (rB) loads
  #pragma unroll
  for (int j = 0; j < 4; ++j)
    *(short8_t*)(wd + (j << 11)) = *(const short8_t*)(s0 + (j << 5));
  short8_t rA0 = *(const short8_t*)LDP(4);
  short8_t rA1 = *(const short8_t*)LDP(5);
  short8_t rA2 = *(const short8_t*)LDP(6);
  short8_t rA3 = *(const short8_t*)LDP(7);
  short8_t rB0 = *(const short8_t*)LDP(8);
  short8_t rB1 = *(const short8_t*)LDP(9);
  short8_t rB2 = *(const short8_t*)LDP(10);
  short8_t rB3 = *(const short8_t*)LDP(11);
  __syncthreads();

  #pragma unroll
  for (int ss = 0; ss < 7; ++ss) {
    short8_t rC0, rC1, rC2, rC3;
    if (ss < 4) {  // issue loads for super-step ss+3 (three phases ahead)
      int kb = (ss + 3) * 4;
      rC0 = *(const short8_t*)LDP(kb + 0);
      rC1 = *(const short8_t*)LDP(kb + 1);
      rC2 = *(const short8_t*)LDP(kb + 2);
      rC3 = *(const short8_t*)LDP(kb + 3);
    }
    const u16* bufc = &stg[ss & 1][0];
    #pragma unroll
    for (int j = 0; j < 4; ++j) {
      int ks = ss * 4 + j;
      short8_t af0 = *(const short8_t*)(pWF0 + (ks << 9));
      short8_t af1 = *(const short8_t*)(pWF1 + (ks << 9));
      short8_t ag0 = *(const short8_t*)(pWG0 + (ks << 9));
      short8_t ag1 = *(const short8_t*)(pWG1 + (ks << 9));
      #pragma unroll
      for (int n = 0; n < 4; ++n) {
        short8_t bv = *(const short8_t*)(bufc + (j << 11) + (n << 9) + (lane << 3));
        accF[0][n] = __builtin_amdgcn_mfma_f32_16x16x32_bf16(af0, bv, accF[0][n], 0, 0, 0);
        accF[1][n] = __builtin_amdgcn_mfma_f32_16x16x32_bf16(af1, bv, accF[1][n], 0, 0, 0);
        accG[0][n] = __builtin_amdgcn_mfma_f32_16x16x32_bf16(ag0, bv, accG[0][n], 0, 0, 0);
        accG[1][n] = __builtin_amdgcn_mfma_f32_16x16x32_bf16(ag1, bv, accG[1][n], 0, 0, 0);
      }
    }
    if (ss < 6) {  // write step ss+1's data (loaded at step ss-2) into other buffer
      u16* wdn = wd + (((ss + 1) & 1) << 13);
      *(short8_t*)(wdn + (0 << 11)) = rA0;
      *(short8_t*)(wdn + (1 << 11)) = rA1;
      *(short8_t*)(wdn + (2 << 11)) = rA2;
      *(short8_t*)(wdn + (3 << 11)) = rA3;
    }
    if (ss < 5) { rA0 = rB0; rA1 = rB1; rA2 = rB2; rA3 = rB3; }
    if (ss < 4) { rB0 = rC0; rB1 = rC1; rB2 = rC2; rB3 = rC3; }
    __syncthreads();
  }
  #undef LDP

  const float* cbF = cb + b * 256;
  const float* cbG = cb + 1024 + b * 256;
  #pragma unroll
  for (int n = 0; n < 4; ++n) {
    int t = tbase + (n << 4) + lrow;
    if (t >= Lz) continue;
    #pragma unroll
    for (int m = 0; m < 2; ++m) {
      int ch0 = chb + (m << 4) + (lk16 << 2);
      f32x4 bf = *(const f32x4*)(cbF + ch0);
      f32x4 bg = *(const f32x4*)(cbG + ch0);
      ushort4 o;
      #pragma unroll
      for (int r = 0; r < 4; ++r) {
        float f = accF[m][n][r] + bf[r];
        float g = accG[m][n][r] + bg[r];
        f = fminf(fmaxf(f, -15.f), 15.f);
        float e2 = __expf(2.f * f);
        float th = 1.f - 2.f * __builtin_amdgcn_rcpf(e2 + 1.f);
        float sg = __builtin_amdgcn_rcpf(1.f + __expf(-g));
        u16 zz = f2bf(th * sg);
        if (r == 0) o.x = zz; else if (r == 1) o.y = zz; else if (r == 2) o.z = zz; else o.w = zz;
      }
      *(ushort4*)(Z + ((long)b * T_IN + t) * 256 + ch0) = o;
    }
  }
}

// ---- skip+res v6h: full-K single stage (1 barrier), 5 ch-slices ----
// Weight loads hoisted into registers BEFORE the z staging + barrier so
// their latency overlaps the stage drain; MFMA reads weights from regs.
__global__ __launch_bounds__(256, 3) void k_skipres6(
    const u16* __restrict__ Zb, const u16* __restrict__ Wskp, const u16* __restrict__ Wres,
    const u16* __restrict__ Xres, float* __restrict__ skip, u16* __restrict__ Xout,
    int Lz, int sl, int lw, int first) {
  __shared__ __align__(16) u16 stg[16384];
  int lane = threadIdx.x & 63, wave = threadIdx.x >> 6;
  int slice = blockIdx.x;
  int tbase = blockIdx.y << 6;
  int b = blockIdx.z;
  bool issk = slice < 2;
  int mt0 = (issk ? slice * 8 : (slice - 2) * 8) + (wave << 1);
  const u16* Wp = issk ? Wskp : Wres;
  int lrow = lane & 15, lk16 = lane >> 4;
  const u16* pW0 = Wp + (((long)mt0 * 8) << 9) + (lane << 3);
  const u16* pW1 = Wp + (((long)(mt0 + 1) * 8) << 9) + (lane << 3);
  // hoist weights into registers (issued before z staging)
  short8_t w0[8], w1[8];
  #pragma unroll
  for (int ks = 0; ks < 8; ++ks) {
    w0[ks] = *(const short8_t*)(pW0 + (ks << 9));
    w1[ks] = *(const short8_t*)(pW1 + (ks << 9));
  }
  const u16* zb = Zb + (long)b * T_IN * 256;
  int r0 = min(tbase + (wave << 4) + lrow, T_IN - 1);
  const u16* sz = zb + (long)r0 * 256 + (lk16 << 3);
  u16* wd = &stg[0] + (wave << 9) + (lane << 3);
  f32x4 zed = {0.f, 0.f, 0.f, 0.f};
  f32x4 acc[2][4];
  #pragma unroll
  for (int m = 0; m < 2; ++m)
    #pragma unroll
    for (int n = 0; n < 4; ++n) acc[m][n] = zed;

  // stage all 8 k-substeps (wave stages frag n=wave for each)
  #pragma unroll
  for (int j = 0; j < 8; ++j)
    *(short8_t*)(wd + (j << 11)) = *(const short8_t*)(sz + (j << 5));
  __syncthreads();

  #pragma unroll
  for (int ks = 0; ks < 8; ++ks) {
    #pragma unroll
    for (int n = 0; n < 4; ++n) {
      short8_t bv = *(const short8_t*)(&stg[0] + (ks << 11) + (n << 9) + (lane << 3));
      acc[0][n] = __builtin_amdgcn_mfma_f32_16x16x32_bf16(w0[ks], bv, acc[0][n], 0, 0, 0);
      acc[1][n] = __builtin_amdgcn_mfma_f32_16x16x32_bf16(w1[ks], bv, acc[1][n], 0, 0, 0);
    }
  }
  #pragma unroll
  for (int n = 0; n < 4; ++n) {
    int tg = tbase + (n << 4) + lrow;
    #pragma unroll
    for (int m = 0; m < 2; ++m) {
      int ch0 = ((mt0 + m) << 4) + (lk16 << 2);
      if (issk) {
        if (tg >= sl && tg < Lz) {
          float* p = skip + ((long)b * T_OUT + (tg - sl)) * 256 + ch0;
          if (first) { *(f32x4*)p = acc[m][n]; }
          else { f32x4 v = *(f32x4*)p; v += acc[m][n]; *(f32x4*)p = v; }
        }
      } else if (tg < Lz) {
        const u16* rp = Xres + ((long)b * T_IN + tg + lw) * 384 + ch0;
        ushort4 rv = *(const ushort4*)rp;
        ushort4 o;
        o.x = f2bf(acc[m][n][0] + bf2f(rv.x));
        o.y = f2bf(acc[m][n][1] + bf2f(rv.y));
        o.z = f2bf(acc[m][n][2] + bf2f(rv.z));
        o.w = f2bf(acc[m][n][3] + bf2f(rv.w));
        *(ushort4*)(Xout + ((long)b * T_IN + tg) * 384 + ch0) = o;
      }
    }
  }
}

// post1: h1 = relu(W1 @ relu(skip) + b1), M=512, K=256; B from f32 skip with inline relu+cvt
__global__ __launch_bounds__(256) void k_post1(
    const float* __restrict__ skip, const u16* __restrict__ Wp,
    const float* __restrict__ b1, u16* __restrict__ h1) {
  int lane = threadIdx.x & 63, wave = threadIdx.x >> 6;
  int b = blockIdx.z, qb = blockIdx.y << 6;
  int tbase = (blockIdx.x << 8) + (wave << 6);
  int lrow = lane & 15, lk = (lane >> 4) << 3;
  int mt0 = qb >> 4;
  f32x4 zed = {0.f, 0.f, 0.f, 0.f};
  f32x4 acc[4][4];
  #pragma unroll
  for (int m = 0; m < 4; ++m)
    #pragma unroll
    for (int n = 0; n < 4; ++n) acc[m][n] = zed;
  const float* sb = skip + (long)b * T_OUT * 256;
  for (int ks = 0; ks < 8; ++ks) {
    short8_t a[4];
    #pragma unroll
    for (int m = 0; m < 4; ++m)
      a[m] = *(const short8_t*)(Wp + ((long)((mt0 + m) * 8 + ks) << 9) + (lane << 3));
    #pragma unroll
    for (int n = 0; n < 4; ++n) {
      int row = tbase + (n << 4) + lrow;
      row = min(row, T_OUT - 1);
      const float* src = sb + (long)row * 256 + (ks << 5) + lk;
      f32x4 v0 = *(const f32x4*)src;
      f32x4 v1 = *(const f32x4*)(src + 4);
      short8_t bv;
      #pragma unroll
      for (int j = 0; j < 4; ++j) bv[j] = (short)f2bf(fmaxf(v0[j], 0.f));
      #pragma unroll
      for (int j = 0; j < 4; ++j) bv[4 + j] = (short)f2bf(fmaxf(v1[j], 0.f));
      #pragma unroll
      for (int m = 0; m < 4; ++m)
        acc[m][n] = __builtin_amdgcn_mfma_f32_16x16x32_bf16(a[m], bv, acc[m][n], 0, 0, 0);
    }
  }
  #pragma unroll
  for (int n = 0; n < 4; ++n) {
    int t = tbase + (n << 4) + lrow;
    if (t >= T_OUT) continue;
    #pragma unroll
    for (int m = 0; m < 4; ++m) {
      int ch0 = qb + (m << 4) + ((lane >> 4) << 2);
      f32x4 bb = *(const f32x4*)(b1 + ch0);
      ushort4 o;
      o.x = f2bf(fmaxf(acc[m][n][0] + bb[0], 0.f));
      o.y = f2bf(fmaxf(acc[m][n][1] + bb[1], 0.f));
      o.z = f2bf(fmaxf(acc[m][n][2] + bb[2], 0.f));
      o.w = f2bf(fmaxf(acc[m][n][3] + bb[3], 0.f));
      *(ushort4*)(h1 + ((long)b * T_OUT + t) * 512 + ch0) = o;
    }
  }
}

// post2 + log_softmax: M=256 (4 waves x 64q), K=512, out f32 [b][q][T_OUT]
__global__ __launch_bounds__(256) void k_post2sm(
    const u16* __restrict__ h1, const u16* __restrict__ Wp,
    const float* __restrict__ b2, float* __restrict__ out) {
  __shared__ float redM[4][64];
  __shared__ float redS[4][64];
  int lane = threadIdx.x & 63, wave = threadIdx.x >> 6;
  int b = blockIdx.z;
  int qb = wave << 6;
  int tb = blockIdx.x << 6;
  int lrow = lane & 15, lk = (lane >> 4) << 3;
  int mt0 = qb >> 4;
  f32x4 zed = {0.f, 0.f, 0.f, 0.f};
  f32x4 acc[4][4];
  #pragma unroll
  for (int m = 0; m < 4; ++m)
    #pragma unroll
    for (int n = 0; n < 4; ++n) acc[m][n] = zed;
  const u16* hb = h1 + (long)b * T_OUT * 512;
  for (int ks = 0; ks < 16; ++ks) {
    short8_t a[4];
    #pragma unroll
    for (int m = 0; m < 4; ++m)
      a[m] = *(const short8_t*)(Wp + ((long)((mt0 + m) * 16 + ks) << 9) + (lane << 3));
    #pragma unroll
    for (int n = 0; n < 4; ++n) {
      int row = tb + (n << 4) + lrow;
      row = min(row, T_OUT - 1);
      short8_t bv = *(const short8_t*)(hb + (long)row * 512 + (ks << 5) + lk);
      #pragma unroll
      for (int m = 0; m < 4; ++m)
        acc[m][n] = __builtin_amdgcn_mfma_f32_16x16x32_bf16(a[m], bv, acc[m][n], 0, 0, 0);
    }
  }
  #pragma unroll
  for (int m = 0; m < 4; ++m) {
    int q0 = qb + (m << 4) + ((lane >> 4) << 2);
    f32x4 bb = *(const f32x4*)(b2 + q0);
    #pragma unroll
    for (int n = 0; n < 4; ++n) acc[m][n] += bb;
  }
  float fm[4], fs[4];
  #pragma unroll
  for (int n = 0; n < 4; ++n) {
    float pm = -1e30f;
    #pragma unroll
    for (int m = 0; m < 4; ++m)
      #pragma unroll
      for (int r = 0; r < 4; ++r) pm = fmaxf(pm, acc[m][n][r]);
    pm = fmaxf(pm, __shfl_xor(pm, 16));
    pm = fmaxf(pm, __shfl_xor(pm, 32));
    if (lane < 16) redM[wave][(n << 4) + lane] = pm;
  }
  __syncthreads();
  #pragma unroll
  for (int n = 0; n < 4; ++n) {
    float mm = redM[0][(n << 4) + lrow];
    mm = fmaxf(mm, redM[1][(n << 4) + lrow]);
    mm = fmaxf(mm, redM[2][(n << 4) + lrow]);
    mm = fmaxf(mm, redM[3][(n << 4) + lrow]);
    fm[n] = mm;
    float ps = 0.f;
    #pragma unroll
    for (int m = 0; m < 4; ++m)
      #pragma unroll
      for (int r = 0; r < 4; ++r) ps += __expf(acc[m][n][r] - mm);
    ps += __shfl_xor(ps, 16);
    ps += __shfl_xor(ps, 32);
    if (lane < 16) redS[wave][(n << 4) + lane] = ps;
  }
  __syncthreads();
  #pragma unroll
  for (int n = 0; n < 4; ++n) {
    float ss = redS[0][(n << 4) + lrow] + redS[1][(n << 4) + lrow] +
               redS[2][(n << 4) + lrow] + redS[3][(n << 4) + lrow];
    fs[n] = fm[n] + logf(ss);
  }
  #pragma unroll
  for (int n = 0; n < 4; ++n) {
    int t = tb + (n << 4) + lrow;
    if (t >= T_OUT) continue;
    #pragma unroll
    for (int m = 0; m < 4; ++m) {
      int q0 = qb + (m << 4) + ((lane >> 4) << 2);
      #pragma unroll
      for (int r = 0; r < 4; ++r)
        out[((long)b * 256 + q0 + r) * T_OUT + t] = acc[m][n][r] - fs[n];
    }
  }
}

extern "C" void kernel_launch(void* const* d_in, const int* in_sizes, int n_in,
                              void* d_out, int out_size, void* d_ws, size_t ws_size,
                              hipStream_t stream) {
  const float* wav       = (const float*)d_in[0];
  const float* lc_sparse = (const float*)d_in[1];
  const float* lc_conv_w = (const float*)d_in[2];
  const float* lc_conv_b = (const float*)d_in[3];
  const float* ups_w[4]  = {(const float*)d_in[4], (const float*)d_in[6], (const float*)d_in[8], (const float*)d_in[10]};
  const float* ups_b[4]  = {(const float*)d_in[5], (const float*)d_in[7], (const float*)d_in[9], (const float*)d_in[11]};
  const float* emb_w     = (const float*)d_in[12];
  const float* emb_b     = (const float*)d_in[13];
  const float* base_w    = (const float*)d_in[14];
  const float* base_b    = (const float*)d_in[15];
  const float* sig_w     = (const float*)d_in[16];
  const float* sig_b     = (const float*)d_in[17];
  const float* gate_w    = (const float*)d_in[18];
  const float* gate_b    = (const float*)d_in[19];
  const float* psig_w    = (const float*)d_in[20];
  const float* pgate_w   = (const float*)d_in[21];
  const float* skp_w     = (const float*)d_in[22];
  const float* res_w     = (const float*)d_in[23];
  const float* post1_w   = (const float*)d_in[24];
  const float* post1_b   = (const float*)d_in[25];
  const float* post2_w   = (const float*)d_in[26];
  const float* post2_b   = (const float*)d_in[27];
  const int* spk         = (const int*)d_in[28];
  const int* jit         = (const int*)d_in[29];
  float* out = (float*)d_out;

  size_t off = 0;
  auto alloc = [&](size_t bytes) -> void* {
    off = (off + 255) & ~(size_t)255;
    void* p = (char*)d_ws + off;
    off += bytes;
    return p;
  };
  u16* wfgF   = (u16*)alloc(20L * 229376 * 2);
  u16* wfgG   = (u16*)alloc(20L * 229376 * 2);
  u16* wskpF  = (u16*)alloc(20L * 65536 * 2);
  u16* wresF  = (u16*)alloc(20L * 98304 * 2);
  u16* wbaseF = (u16*)alloc(384L * 256 * 2);
  u16* wp1F   = (u16*)alloc(512L * 256 * 2);
  u16* wp2F   = (u16*)alloc(256L * 512 * 2);
  float* wtc1 = (float*)alloc(5L * 640 * 128 * 4);
  float* wtc2 = (float*)alloc(4L * 512 * 128 * 4);
  float* wtc3 = (float*)alloc(4L * 512 * 128 * 4);
  u16* wtc4F  = (u16*)alloc(4L * 65536 * 2);
  float* cbias = (float*)alloc(20L * 2 * 4 * 256 * 4);
  float* gc    = (float*)alloc(4L * 128 * 4);
  u16* lcbf    = (u16*)alloc(4L * T_IN * 128 * 2);
  u16* xA      = (u16*)alloc(4L * T_IN * 384 * 2);
  u16* xB      = (u16*)alloc(4L * T_IN * 384 * 2);
  u16* zbuf    = (u16*)alloc(4L * T_IN * 256 * 2);
  float* skip  = (float*)alloc(4L * T_OUT * 256 * 4);
  // temporal aliases (stream-ordered, lifetimes disjoint):
  float* lcs0 = (float*)zbuf;
  float* lcs1 = lcs0 + 4L * 128 * 64;
  float* lcs2 = lcs1 + 4L * 128 * 290;
  float* lcs3 = lcs2 + 4L * 128 * 1148;
  u16* im3    = xB;
  u16* wavT   = (u16*)skip;
  u16* h1bf   = xA;
  (void)ws_size; (void)in_sizes; (void)n_in; (void)out_size;

  // weight packs
  k_pack_frag_gau<<<4480, 256, 0, stream>>>(sig_w, gate_w, psig_w, pgate_w, wfgF, wfgG);
  k_pack_frag<<<1280, 256, 0, stream>>>(skp_w, wskpF, 256, 256, 20, 256L * 256);
  k_pack_frag<<<1920, 256, 0, stream>>>(res_w, wresF, 384, 256, 20, 384L * 256);
  k_pack_frag<<<96, 256, 0, stream>>>(base_w, wbaseF, 384, 256, 1, 0);
  k_pack_frag<<<128, 256, 0, stream>>>(post1_w, wp1F, 512, 256, 1, 0);
  k_pack_frag<<<128, 256, 0, stream>>>(post2_w, wp2F, 256, 512, 1, 0);
  k_pack_tconv<<<320, 256, 0, stream>>>(ups_w[0], wtc1, 5, 25, 5);
  k_pack_tconv<<<256, 256, 0, stream>>>(ups_w[1], wtc2, 4, 16, 4);
  k_pack_tconv<<<256, 256, 0, stream>>>(ups_w[2], wtc3, 4, 16, 4);
  k_pack_tc4f<<<256, 256, 0, stream>>>(ups_w[3], wtc4F);
  k_gc<<<1, 512, 0, stream>>>(emb_w, emb_b, spk, gc);
  k_cbias<<<dim3(20, 8), 256, 0, stream>>>(psig_w, pgate_w, sig_b, gate_b, gc, cbias);

  // local-conditioning chain
  k_lc0<<<dim3(4, 62), 128, 0, stream>>>(lc_sparse, jit, lc_conv_w, lc_conv_b, lcs0);
  k_tconvg<5><<<dim3(1, 10, 4), 256, 0, stream>>>(lcs0, 62, 64, lcs1, 290, 290, wtc1, ups_b[0], 5);
  k_tconvg<4><<<dim3(5, 8, 4), 256, 0, stream>>>(lcs1, 290, 290, lcs2, 1148, 1148, wtc2, ups_b[1], 4);
  k_tconvg<4><<<dim3(18, 8, 4), 256, 0, stream>>>(lcs2, 1148, 1148, lcs3, 4580, 4580, wtc3, ups_b[2], 4);
  k_im2col3<<<2048, 256, 0, stream>>>(lcs3, im3);
  k_tconv4m<<<dim3(18, 8, 4), 256, 0, stream>>>(im3, wtc4F, ups_b[3], lcbf);

  // wav transpose + base 1x1 conv (MFMA) -> xA t-major bf16
  k_wav_t<<<dim3(287, 8, 4), 256, 0, stream>>>(wav, wavT);
  k_basem<<<dim3(72, 6, 4), 256, 0, stream>>>(wavT, wbaseF, base_b, xA);

  static const int DILS[20] = {1, 2, 4, 8, 16, 32, 64, 128, 256, 512,
                               1, 2, 4, 8, 16, 32, 64, 128, 256, 512};
  int cum = 0;
  u16* xc = xA; u16* xn = xB;
  for (int l = 0; l < 20; ++l) {
    int dd = DILS[l], lw = dd, cl = cum + lw;
    int Lz = T_IN - cl;
    int sl = 2046 - cl;
    int nt = (Lz + 63) / 64;
    int gx = 16 * ((nt + 7) >> 3);
    k_gau6<<<dim3(gx, 1, 4), 256, 0, stream>>>(
        xc, lcbf, wfgF + (long)l * 229376, wfgG + (long)l * 229376,
        cbias + (long)l * 2048, zbuf, Lz, dd, cl, nt);
    int nsl = (l == 19) ? 2 : 5;
    k_skipres6<<<dim3(nsl, nt, 4), 256, 0, stream>>>(
        zbuf, wskpF + (long)l * 65536, wresF + (long)l * 98304,
        xc, skip, xn, Lz, sl, lw, (l == 0) ? 1 : 0);
    cum = cl;
    u16* t = xc; xc = xn; xn = t;
  }

  k_post1<<<dim3(64, 8, 4), 256, 0, stream>>>(skip, wp1F, post1_b, h1bf);
  k_post2sm<<<dim3(255, 1, 4), 256, 0, stream>>>(h1bf, wp2F, post2_b, out);
}

// Round 18
// 3461.525 us; speedup vs baseline: 1.0868x; 1.0868x over previous
//
#include <hip/hip_runtime.h>
#include <hip/hip_bf16.h>
#include <math.h>

// WaveNet forward on gfx950 — round 18: compose r16's gau6 (2-deep reg
// pipeline, 89us, no spills) with r17's skipres weight-hoist (isolated
// -104us total). Everything else = r15/r16 base.

#define T_IN 18308
#define T_OUT 16262

typedef unsigned short u16;
typedef unsigned int u32;
typedef __attribute__((ext_vector_type(8))) short short8_t;
typedef __attribute__((ext_vector_type(4))) float f32x4;

__device__ __forceinline__ float bf2f(u16 h) { return __uint_as_float(((u32)h) << 16); }
__device__ __forceinline__ u16 f2bf(float f) {
  u32 u = __float_as_uint(f);
  return (u16)((u + 0x7fffu + ((u >> 16) & 1u)) >> 16);
}

// ---- MFMA fragment packing ----
// Frag layout per (mt,ks): dst[(mt*nks+ks)*512 + lane*8 + j] = W[mt*16+(lane&15)][ks*32+(lane>>4)*8+j]
__global__ void k_pack_frag(const float* __restrict__ src, u16* __restrict__ dst,
                            int M, int K, int L, long src_lstride) {
  int nks = K >> 5;
  long per = (long)M * K;
  long total = per * L;
  for (long idx = blockIdx.x * (long)blockDim.x + threadIdx.x; idx < total; idx += (long)gridDim.x * blockDim.x) {
    int l = (int)(idx / per); long r = idx - (long)l * per;
    int j = (int)(r & 7); int lane = (int)((r >> 3) & 63); int fid = (int)(r >> 9);
    int ks = fid % nks; int mt = fid / nks;
    int row = mt * 16 + (lane & 15);
    int col = ks * 32 + ((lane >> 4) << 3) + j;
    dst[idx] = f2bf(src[l * src_lstride + (long)row * K + col]);
  }
}

// GAU fused weights: logical W[l][256][896]: k<384 tap0, k<768 tap1, else psig(lc chans 0..127)
__global__ void k_pack_frag_gau(const float* __restrict__ sig_w, const float* __restrict__ gate_w,
                                const float* __restrict__ psig_w, const float* __restrict__ pgate_w,
                                u16* __restrict__ dstF, u16* __restrict__ dstG) {
  const long per = 229376; // 16mt * 28ks * 512
  long total = per * 20;
  for (long idx = blockIdx.x * (long)blockDim.x + threadIdx.x; idx < total; idx += (long)gridDim.x * blockDim.x) {
    int l = (int)(idx / per); long r = idx - (long)l * per;
    int j = (int)(r & 7); int lane = (int)((r >> 3) & 63); int fid = (int)(r >> 9);
    int ks = fid % 28; int mt = fid / 28;
    int row = mt * 16 + (lane & 15);
    int k = ks * 32 + ((lane >> 4) << 3) + j;
    float vF, vG;
    if (k < 384) {
      vF = sig_w[(((long)l * 256 + row) * 384 + k) * 2 + 0];
      vG = gate_w[(((long)l * 256 + row) * 384 + k) * 2 + 0];
    } else if (k < 768) {
      vF = sig_w[(((long)l * 256 + row) * 384 + (k - 384)) * 2 + 1];
      vG = gate_w[(((long)l * 256 + row) * 384 + (k - 384)) * 2 + 1];
    } else {
      vF = psig_w[((long)l * 256 + row) * 256 + (k - 768)];
      vG = pgate_w[((long)l * 256 + row) * 256 + (k - 768)];
    }
    dstF[idx] = f2bf(vF);
    dstG[idx] = f2bf(vG);
  }
}

// tconv per-phase weight pack (f32, stages 1-3): dst[p][i*nk+m][o] = w[i][o][K-1-(S-1-p)-m*S]
__global__ void k_pack_tconv(const float* __restrict__ w, float* __restrict__ dst,
                             int S, int K, int nk) {
  int Ktot = 128 * nk;
  long total = (long)S * Ktot * 128;
  for (long idx = blockIdx.x * (long)blockDim.x + threadIdx.x; idx < total; idx += (long)gridDim.x * blockDim.x) {
    int o = (int)(idx & 127);
    long tmp = idx >> 7;
    int k = (int)(tmp % Ktot);
    int p = (int)(tmp / Ktot);
    int i = k / nk, m = k % nk;
    dst[idx] = w[((long)i * 128 + o) * K + (K - 1 - (S - 1 - p) - m * S)];
  }
}

// stage-4 tconv weights, fragment-packed per phase: M=128, K=512 (k = i*4+m), S=4, KW=16
__global__ void k_pack_tc4f(const float* __restrict__ w, u16* __restrict__ dst) {
  const long perp = 65536; // 8mt * 16ks * 512
  long total = perp * 4;
  for (long idx = blockIdx.x * (long)blockDim.x + threadIdx.x; idx < total; idx += (long)gridDim.x * blockDim.x) {
    int p = (int)(idx / perp); long r = idx - (long)p * perp;
    int j = (int)(r & 7); int lane = (int)((r >> 3) & 63); int fid = (int)(r >> 9);
    int ks = fid & 15; int mt = fid >> 4;
    int o = mt * 16 + (lane & 15);
    int k = ks * 32 + ((lane >> 4) << 3) + j;
    int i = k >> 2, m = k & 3;
    dst[idx] = f2bf(w[((long)i * 128 + o) * 16 + (12 + p - 4 * m)]);
  }
}

// im2col for stage-4 tconv input: dst[b][j][i*4+m] = lcs3[b][i][j+m]  (bf16)
__global__ void k_im2col3(const float* __restrict__ lcs3, u16* __restrict__ dst) {
  long total = 4L * 4580 * 512;
  for (long idx = blockIdx.x * (long)blockDim.x + threadIdx.x; idx < total; idx += (long)gridDim.x * blockDim.x) {
    int col = (int)(idx & 511);
    long t2 = idx >> 9;
    int jj = (int)(t2 % 4580);
    int b = (int)(t2 / 4580);
    int i = col >> 2, m = col & 3;
    float v = (jj + m < 4580) ? lcs3[((long)b * 128 + i) * 4580 + jj + m] : 0.0f;
    dst[idx] = f2bf(v);
  }
}

__global__ void k_gc(const float* __restrict__ emb_w, const float* __restrict__ emb_b,
                     const int* __restrict__ spk, float* __restrict__ gc) {
  int i = threadIdx.x + blockIdx.x * blockDim.x;
  if (i < 512) { int b = i / 128, g = i % 128; gc[b * 128 + g] = emb_w[g * 40 + spk[b]] + emb_b[g]; }
}

__global__ void k_cbias(const float* __restrict__ psig_w, const float* __restrict__ pgate_w,
                        const float* __restrict__ sig_b, const float* __restrict__ gate_b,
                        const float* __restrict__ gc, float* __restrict__ cbias) {
  int l = blockIdx.x; int fg = blockIdx.y >> 2; int b = blockIdx.y & 3; int c = threadIdx.x;
  const float* p = fg ? pgate_w : psig_w;
  const float* bb = fg ? gate_b : sig_b;
  float acc = bb[l * 256 + c];
  const float* prow = p + ((long)(l * 256 + c)) * 256 + 128;
  const float* g = gc + b * 128;
  for (int k = 0; k < 128; ++k) acc += prow[k] * g[k];
  cbias[((l * 2 + fg) * 4 + b) * 256 + c] = acc;
}

// jitter-gather + conv3 (VALID): out (B,128,62) f32 ch-major, stride 64
__global__ void k_lc0(const float* __restrict__ lc_sparse, const int* __restrict__ jit,
                      const float* __restrict__ w, const float* __restrict__ bias, float* __restrict__ out) {
  int b = blockIdx.x; int t = blockIdx.y; int co = threadIdx.x; // 128
  __shared__ float xs[64][3];
  for (int i = threadIdx.x; i < 192; i += blockDim.x) {
    int ci = i / 3, kk = i % 3;
    xs[ci][kk] = lc_sparse[((long)b * 64 + ci) * 64 + jit[b * 64 + t + kk]];
  }
  __syncthreads();
  float acc = bias[co];
  #pragma unroll 8
  for (int ci = 0; ci < 64; ++ci) {
    const float* wr = w + ((long)co * 64 + ci) * 3;
    acc += wr[0] * xs[ci][0] + wr[1] * xs[ci][1] + wr[2] * xs[ci][2];
  }
  out[((long)b * 128 + co) * 64 + t] = acc;
}

// Transposed conv stages 1-3 (f32 tiled GEMM, small) — out f32 ch-major
template<int NK>
__global__ __launch_bounds__(256) void k_tconvg(
    const float* __restrict__ xin, int Lin, int xstride,
    float* __restrict__ yout, int Lout, int ostride,
    const float* __restrict__ wp, const float* __restrict__ bias, int S) {
  const int Ktot = 128 * NK;
  __shared__ __align__(16) float Ws[32][64];
  __shared__ __align__(16) float Xs[32][64];
  int b = blockIdx.z;
  int p = blockIdx.y >> 1, bm0 = (blockIdx.y & 1) * 64;
  int j0 = blockIdx.x * 64;
  int tid = threadIdx.x, tn = tid & 15, tm = tid >> 4;
  float acc[4][4] = {};
  int kchunks = Ktot / 32;
  for (int kc = 0; kc < kchunks; ++kc) {
    int k0 = kc * 32;
    {
      int kk = tid >> 3, m8 = (tid & 7) * 8;
      const float* src = wp + ((long)p * Ktot + k0 + kk) * 128 + bm0 + m8;
      float4 f1 = *(const float4*)src;
      float4 f2 = *(const float4*)(src + 4);
      Ws[kk][m8 + 0] = f1.x; Ws[kk][m8 + 1] = f1.y; Ws[kk][m8 + 2] = f1.z; Ws[kk][m8 + 3] = f1.w;
      Ws[kk][m8 + 4] = f2.x; Ws[kk][m8 + 5] = f2.y; Ws[kk][m8 + 6] = f2.z; Ws[kk][m8 + 7] = f2.w;
    }
    #pragma unroll
    for (int rr = 0; rr < 8; ++rr) {
      int kk = rr * 4 + (tid >> 6), tt = tid & 63;
      int k = k0 + kk;
      int i = k / NK, m = k % NK;
      int j = j0 + tt;
      Xs[kk][tt] = (j + m < Lin) ? xin[((long)(b * 128 + i)) * xstride + j + m] : 0.0f;
    }
    __syncthreads();
    #pragma unroll 8
    for (int kk = 0; kk < 32; ++kk) {
      float av[4], bv[4];
      #pragma unroll
      for (int i = 0; i < 4; ++i) av[i] = Ws[kk][tm * 4 + i];
      #pragma unroll
      for (int j = 0; j < 4; ++j) bv[j] = Xs[kk][tn * 4 + j];
      #pragma unroll
      for (int i = 0; i < 4; ++i)
        #pragma unroll
        for (int j = 0; j < 4; ++j) acc[i][j] = fmaf(av[i], bv[j], acc[i][j]);
    }
    __syncthreads();
  }
  #pragma unroll
  for (int jj = 0; jj < 4; ++jj) {
    int j = j0 + tn * 4 + jj;
    int t = j * S + p;
    if (t >= Lout) continue;
    #pragma unroll
    for (int i = 0; i < 4; ++i) {
      int o = bm0 + tm * 4 + i;
      yout[((long)b * 128 + o) * ostride + t] = acc[i][jj] + bias[o];
    }
  }
}

// stage-4 tconv via MFMA: B = im2col [b][j][512], per-phase packed W, out lcbf [b][t=4j+p][128]
__global__ __launch_bounds__(256) void k_tconv4m(
    const u16* __restrict__ im, const u16* __restrict__ Wp4,
    const float* __restrict__ bias, u16* __restrict__ out) {
  int lane = threadIdx.x & 63, wave = threadIdx.x >> 6;
  int b = blockIdx.z;
  int p = blockIdx.y >> 1, chb = (blockIdx.y & 1) << 6;
  int tbase = (blockIdx.x << 8) + (wave << 6);
  int lrow = lane & 15, lk = (lane >> 4) << 3;
  int mt0 = chb >> 4;
  const u16* Wp = Wp4 + (long)p * 65536;
  f32x4 zed = {0.f, 0.f, 0.f, 0.f};
  f32x4 acc[4][4];
  #pragma unroll
  for (int m = 0; m < 4; ++m)
    #pragma unroll
    for (int n = 0; n < 4; ++n) acc[m][n] = zed;
  const u16* ib = im + (long)b * 4580 * 512;
  for (int ks = 0; ks < 16; ++ks) {
    short8_t a[4];
    #pragma unroll
    for (int m = 0; m < 4; ++m)
      a[m] = *(const short8_t*)(Wp + ((long)((mt0 + m) * 16 + ks) << 9) + (lane << 3));
    #pragma unroll
    for (int n = 0; n < 4; ++n) {
      int j = tbase + (n << 4) + lrow;
      j = min(j, 4579);
      short8_t bv = *(const short8_t*)(ib + (long)j * 512 + (ks << 5) + lk);
      #pragma unroll
      for (int m = 0; m < 4; ++m)
        acc[m][n] = __builtin_amdgcn_mfma_f32_16x16x32_bf16(a[m], bv, acc[m][n], 0, 0, 0);
    }
  }
  #pragma unroll
  for (int n = 0; n < 4; ++n) {
    int j = tbase + (n << 4) + lrow;
    int t = j * 4 + p;
    if (t >= T_IN) continue;
    #pragma unroll
    for (int m = 0; m < 4; ++m) {
      int ch0 = chb + (m << 4) + ((lane >> 4) << 2);
      f32x4 bb = *(const f32x4*)(bias + ch0);
      ushort4 o;
      o.x = f2bf(acc[m][n][0] + bb[0]);
      o.y = f2bf(acc[m][n][1] + bb[1]);
      o.z = f2bf(acc[m][n][2] + bb[2]);
      o.w = f2bf(acc[m][n][3] + bb[3]);
      *(ushort4*)(out + ((long)b * T_IN + t) * 128 + ch0) = o;
    }
  }
}

// wav transpose: f32 ch-major [b][256][T] -> bf16 t-major [b][T][256]
__global__ __launch_bounds__(256) void k_wav_t(const float* __restrict__ wav, u16* __restrict__ dst) {
  __shared__ float xs[32][65];
  int b = blockIdx.z, c0 = blockIdx.y * 32, t0 = blockIdx.x * 64;
  int tid = threadIdx.x;
  #pragma unroll
  for (int i = 0; i < 8; ++i) {
    int idx = tid + i * 256;
    int c = idx >> 6, tl = idx & 63;
    int t = t0 + tl; if (t >= T_IN) t = T_IN - 1;
    xs[c][tl] = wav[((long)b * 256 + c0 + c) * T_IN + t];
  }
  __syncthreads();
  #pragma unroll
  for (int i = 0; i < 8; ++i) {
    int idx = tid + i * 256;
    int tl = idx >> 5, c = idx & 31;
    int t = t0 + tl;
    if (t < T_IN) dst[((long)b * T_IN + t) * 256 + c0 + c] = f2bf(xs[c][tl]);
  }
}

// base 1x1 conv MFMA: M=384, K=256, B = wavT, out xA bf16 t-major [b][t][384]
__global__ __launch_bounds__(256) void k_basem(
    const u16* __restrict__ wavT, const u16* __restrict__ Wp,
    const float* __restrict__ bias, u16* __restrict__ X) {
  int lane = threadIdx.x & 63, wave = threadIdx.x >> 6;
  int b = blockIdx.z, chb = blockIdx.y << 6;
  int tbase = (blockIdx.x << 8) + (wave << 6);
  int lrow = lane & 15, lk = (lane >> 4) << 3;
  int mt0 = chb >> 4;
  f32x4 zed = {0.f, 0.f, 0.f, 0.f};
  f32x4 acc[4][4];
  #pragma unroll
  for (int m = 0; m < 4; ++m)
    #pragma unroll
    for (int n = 0; n < 4; ++n) acc[m][n] = zed;
  const u16* xb = wavT + (long)b * T_IN * 256;
  for (int ks = 0; ks < 8; ++ks) {
    short8_t a[4];
    #pragma unroll
    for (int m = 0; m < 4; ++m)
      a[m] = *(const short8_t*)(Wp + ((long)((mt0 + m) * 8 + ks) << 9) + (lane << 3));
    #pragma unroll
    for (int n = 0; n < 4; ++n) {
      int row = tbase + (n << 4) + lrow;
      row = min(row, T_IN - 1);
      short8_t bv = *(const short8_t*)(xb + (long)row * 256 + (ks << 5) + lk);
      #pragma unroll
      for (int m = 0; m < 4; ++m)
        acc[m][n] = __builtin_amdgcn_mfma_f32_16x16x32_bf16(a[m], bv, acc[m][n], 0, 0, 0);
    }
  }
  #pragma unroll
  for (int n = 0; n < 4; ++n) {
    int t = tbase + (n << 4) + lrow;
    if (t >= T_IN) continue;
    #pragma unroll
    for (int m = 0; m < 4; ++m) {
      int ch0 = chb + (m << 4) + ((lane >> 4) << 2);
      f32x4 bb = *(const f32x4*)(bias + ch0);
      ushort4 o;
      o.x = f2bf(acc[m][n][0] + bb[0]);
      o.y = f2bf(acc[m][n][1] + bb[1]);
      o.z = f2bf(acc[m][n][2] + bb[2]);
      o.w = f2bf(acc[m][n][3] + bb[3]);
      *(ushort4*)(X + ((long)b * T_IN + t) * 384 + ch0) = o;
    }
  }
}

// ---- GAU v6p (r16): 4-wave blocks, T=64, KU=4 (7 barriers), 2-deep reg pipeline ----
// Loads for super-step ss+2 issued at top of step ss; step ss+1's regs
// written at bottom of step ss -> each load covered by two MFMA phases.
__global__ __launch_bounds__(256, 3) void k_gau6(
    const u16* __restrict__ Xc, const u16* __restrict__ Lc,
    const u16* __restrict__ WpF, const u16* __restrict__ WpG,
    const float* __restrict__ cb, u16* __restrict__ Z,
    int Lz, int d, int cl, int nt) {
  __shared__ __align__(16) u16 stg[2][8192];
  int lane = threadIdx.x & 63, wave = threadIdx.x >> 6;
  int bx = blockIdx.x;
  int tb = ((bx >> 4) << 3) + (bx & 7);
  int chh = (bx >> 3) & 1;
  if (tb >= nt) return;
  int tbase = tb << 6;
  int b = blockIdx.z;
  int chb = (chh << 7) + (wave << 5);
  int mt0 = chb >> 4;
  int lrow = lane & 15, lk16 = lane >> 4;
  const u16* xb = Xc + (long)b * T_IN * 384;
  const u16* lb = Lc + (long)b * T_IN * 128;
  const u16* pWF0 = WpF + (((long)mt0 * 28) << 9) + (lane << 3);
  const u16* pWF1 = WpF + (((long)(mt0 + 1) * 28) << 9) + (lane << 3);
  const u16* pWG0 = WpG + (((long)mt0 * 28) << 9) + (lane << 3);
  const u16* pWG1 = WpG + (((long)(mt0 + 1) * 28) << 9) + (lane << 3);
  int r0 = tbase + (wave << 4) + lrow;
  const u16* s0 = xb + (long)min(r0, T_IN - 1) * 384 + (lk16 << 3);
  const u16* s1 = xb + (long)min(r0 + d, T_IN - 1) * 384 + (lk16 << 3);
  const u16* s2 = lb + (long)min(r0 + cl, T_IN - 1) * 128 + (lk16 << 3);
  u16* wd = &stg[0][0] + (wave << 9) + (lane << 3);
  // compile-time segmented load pointer for k-substep kn
  #define LDP(kn) ((kn) < 12 ? (s0 + ((kn) << 5)) : (kn) < 24 ? (s1 + (((kn) - 12) << 5)) : (s2 + (((kn) - 24) << 5)))

  f32x4 zed = {0.f, 0.f, 0.f, 0.f};
  f32x4 accF[2][4], accG[2][4];
  #pragma unroll
  for (int m = 0; m < 2; ++m)
    #pragma unroll
    for (int n = 0; n < 4; ++n) { accF[m][n] = zed; accG[m][n] = zed; }

  // prologue: stage super-step 0 (ks 0..3) into buf0; issue step-1 loads (ks 4..7)
  #pragma unroll
  for (int j = 0; j < 4; ++j)
    *(short8_t*)(wd + (j << 11)) = *(const short8_t*)(s0 + (j << 5));
  short8_t rA0 = *(const short8_t*)(s0 + (4 << 5));
  short8_t rA1 = *(const short8_t*)(s0 + (5 << 5));
  short8_t rA2 = *(const short8_t*)(s0 + (6 << 5));
  short8_t rA3 = *(const short8_t*)(s0 + (7 << 5));
  __syncthreads();

  #pragma unroll
  for (int ss = 0; ss < 7; ++ss) {
    short8_t rB0, rB1, rB2, rB3;
    if (ss < 5) {  // issue loads for super-step ss+2 (two phases ahead)
      int kb = (ss + 2) * 4;
      rB0 = *(const short8_t*)LDP(kb + 0);
      rB1 = *(const short8_t*)LDP(kb + 1);
      rB2 = *(const short8_t*)LDP(kb + 2);
      rB3 = *(const short8_t*)LDP(kb + 3);
    }
    const u16* bufc = &stg[ss & 1][0];
    #pragma unroll
    for (int j = 0; j < 4; ++j) {
      int ks = ss * 4 + j;
      short8_t af0 = *(const short8_t*)(pWF0 + (ks << 9));
      short8_t af1 = *(const short8_t*)(pWF1 + (ks << 9));
      short8_t ag0 = *(const short8_t*)(pWG0 + (ks << 9));
      short8_t ag1 = *(const short8_t*)(pWG1 + (ks << 9));
      #pragma unroll
      for (int n = 0; n < 4; ++n) {
        short8_t bv = *(const short8_t*)(bufc + (j << 11) + (n << 9) + (lane << 3));
        accF[0][n] = __builtin_amdgcn_mfma_f32_16x16x32_bf16(af0, bv, accF[0][n], 0, 0, 0);
        accF[1][n] = __builtin_amdgcn_mfma_f32_16x16x32_bf16(af1, bv, accF[1][n], 0, 0, 0);
        accG[0][n] = __builtin_amdgcn_mfma_f32_16x16x32_bf16(ag0, bv, accG[0][n], 0, 0, 0);
        accG[1][n] = __builtin_amdgcn_mfma_f32_16x16x32_bf16(ag1, bv, accG[1][n], 0, 0, 0);
      }
    }
    if (ss < 6) {  // write step ss+1's data (held since step ss-1) into other buffer
      u16* wdn = wd + (((ss + 1) & 1) << 13);
      *(short8_t*)(wdn + (0 << 11)) = rA0;
      *(short8_t*)(wdn + (1 << 11)) = rA1;
      *(short8_t*)(wdn + (2 << 11)) = rA2;
      *(short8_t*)(wdn + (3 << 11)) = rA3;
    }
    if (ss < 5) { rA0 = rB0; rA1 = rB1; rA2 = rB2; rA3 = rB3; }
    __syncthreads();
  }
  #undef LDP

  const float* cbF = cb + b * 256;
  const float* cbG = cb + 1024 + b * 256;
  #pragma unroll
  for (int n = 0; n < 4; ++n) {
    int t = tbase + (n << 4) + lrow;
    if (t >= Lz) continue;
    #pragma unroll
    for (int m = 0; m < 2; ++m) {
      int ch0 = chb + (m << 4) + (lk16 << 2);
      f32x4 bf = *(const f32x4*)(cbF + ch0);
      f32x4 bg = *(const f32x4*)(cbG + ch0);
      ushort4 o;
      #pragma unroll
      for (int r = 0; r < 4; ++r) {
        float f = accF[m][n][r] + bf[r];
        float g = accG[m][n][r] + bg[r];
        f = fminf(fmaxf(f, -15.f), 15.f);
        float e2 = __expf(2.f * f);
        float th = 1.f - 2.f * __builtin_amdgcn_rcpf(e2 + 1.f);
        float sg = __builtin_amdgcn_rcpf(1.f + __expf(-g));
        u16 zz = f2bf(th * sg);
        if (r == 0) o.x = zz; else if (r == 1) o.y = zz; else if (r == 2) o.z = zz; else o.w = zz;
      }
      *(ushort4*)(Z + ((long)b * T_IN + t) * 256 + ch0) = o;
    }
  }
}

// ---- skip+res v6h (r17): full-K single stage (1 barrier), 5 ch-slices ----
// Weight loads hoisted into registers BEFORE the z staging + barrier so
// their latency overlaps the stage drain; MFMA reads weights from regs.
__global__ __launch_bounds__(256, 3) void k_skipres6(
    const u16* __restrict__ Zb, const u16* __restrict__ Wskp, const u16* __restrict__ Wres,
    const u16* __restrict__ Xres, float* __restrict__ skip, u16* __restrict__ Xout,
    int Lz, int sl, int lw, int first) {
  __shared__ __align__(16) u16 stg[16384];
  int lane = threadIdx.x & 63, wave = threadIdx.x >> 6;
  int slice = blockIdx.x;
  int tbase = blockIdx.y << 6;
  int b = blockIdx.z;
  bool issk = slice < 2;
  int mt0 = (issk ? slice * 8 : (slice - 2) * 8) + (wave << 1);
  const u16* Wp = issk ? Wskp : Wres;
  int lrow = lane & 15, lk16 = lane >> 4;
  const u16* pW0 = Wp + (((long)mt0 * 8) << 9) + (lane << 3);
  const u16* pW1 = Wp + (((long)(mt0 + 1) * 8) << 9) + (lane << 3);
  // hoist weights into registers (issued before z staging)
  short8_t w0[8], w1[8];
  #pragma unroll
  for (int ks = 0; ks < 8; ++ks) {
    w0[ks] = *(const short8_t*)(pW0 + (ks << 9));
    w1[ks] = *(const short8_t*)(pW1 + (ks << 9));
  }
  const u16* zb = Zb + (long)b * T_IN * 256;
  int r0 = min(tbase + (wave << 4) + lrow, T_IN - 1);
  const u16* sz = zb + (long)r0 * 256 + (lk16 << 3);
  u16* wd = &stg[0] + (wave << 9) + (lane << 3);
  f32x4 zed = {0.f, 0.f, 0.f, 0.f};
  f32x4 acc[2][4];
  #pragma unroll
  for (int m = 0; m < 2; ++m)
    #pragma unroll
    for (int n = 0; n < 4; ++n) acc[m][n] = zed;

  // stage all 8 k-substeps (wave stages frag n=wave for each)
  #pragma unroll
  for (int j = 0; j < 8; ++j)
    *(short8_t*)(wd + (j << 11)) = *(const short8_t*)(sz + (j << 5));
  __syncthreads();

  #pragma unroll
  for (int ks = 0; ks < 8; ++ks) {
    #pragma unroll
    for (int n = 0; n < 4; ++n) {
      short8_t bv = *(const short8_t*)(&stg[0] + (ks << 11) + (n << 9) + (lane << 3));
      acc[0][n] = __builtin_amdgcn_mfma_f32_16x16x32_bf16(w0[ks], bv, acc[0][n], 0, 0, 0);
      acc[1][n] = __builtin_amdgcn_mfma_f32_16x16x32_bf16(w1[ks], bv, acc[1][n], 0, 0, 0);
    }
  }
  #pragma unroll
  for (int n = 0; n < 4; ++n) {
    int tg = tbase + (n << 4) + lrow;
    #pragma unroll
    for (int m = 0; m < 2; ++m) {
      int ch0 = ((mt0 + m) << 4) + (lk16 << 2);
      if (issk) {
        if (tg >= sl && tg < Lz) {
          float* p = skip + ((long)b * T_OUT + (tg - sl)) * 256 + ch0;
          if (first) { *(f32x4*)p = acc[m][n]; }
          else { f32x4 v = *(f32x4*)p; v += acc[m][n]; *(f32x4*)p = v; }
        }
      } else if (tg < Lz) {
        const u16* rp = Xres + ((long)b * T_IN + tg + lw) * 384 + ch0;
        ushort4 rv = *(const ushort4*)rp;
        ushort4 o;
        o.x = f2bf(acc[m][n][0] + bf2f(rv.x));
        o.y = f2bf(acc[m][n][1] + bf2f(rv.y));
        o.z = f2bf(acc[m][n][2] + bf2f(rv.z));
        o.w = f2bf(acc[m][n][3] + bf2f(rv.w));
        *(ushort4*)(Xout + ((long)b * T_IN + tg) * 384 + ch0) = o;
      }
    }
  }
}

// post1: h1 = relu(W1 @ relu(skip) + b1), M=512, K=256; B from f32 skip with inline relu+cvt
__global__ __launch_bounds__(256) void k_post1(
    const float* __restrict__ skip, const u16* __restrict__ Wp,
    const float* __restrict__ b1, u16* __restrict__ h1) {
  int lane = threadIdx.x & 63, wave = threadIdx.x >> 6;
  int b = blockIdx.z, qb = blockIdx.y << 6;
  int tbase = (blockIdx.x << 8) + (wave << 6);
  int lrow = lane & 15, lk = (lane >> 4) << 3;
  int mt0 = qb >> 4;
  f32x4 zed = {0.f, 0.f, 0.f, 0.f};
  f32x4 acc[4][4];
  #pragma unroll
  for (int m = 0; m < 4; ++m)
    #pragma unroll
    for (int n = 0; n < 4; ++n) acc[m][n] = zed;
  const float* sb = skip + (long)b * T_OUT * 256;
  for (int ks = 0; ks < 8; ++ks) {
    short8_t a[4];
    #pragma unroll
    for (int m = 0; m < 4; ++m)
      a[m] = *(const short8_t*)(Wp + ((long)((mt0 + m) * 8 + ks) << 9) + (lane << 3));
    #pragma unroll
    for (int n = 0; n < 4; ++n) {
      int row = tbase + (n << 4) + lrow;
      row = min(row, T_OUT - 1);
      const float* src = sb + (long)row * 256 + (ks << 5) + lk;
      f32x4 v0 = *(const f32x4*)src;
      f32x4 v1 = *(const f32x4*)(src + 4);
      short8_t bv;
      #pragma unroll
      for (int j = 0; j < 4; ++j) bv[j] = (short)f2bf(fmaxf(v0[j], 0.f));
      #pragma unroll
      for (int j = 0; j < 4; ++j) bv[4 + j] = (short)f2bf(fmaxf(v1[j], 0.f));
      #pragma unroll
      for (int m = 0; m < 4; ++m)
        acc[m][n] = __builtin_amdgcn_mfma_f32_16x16x32_bf16(a[m], bv, acc[m][n], 0, 0, 0);
    }
  }
  #pragma unroll
  for (int n = 0; n < 4; ++n) {
    int t = tbase + (n << 4) + lrow;
    if (t >= T_OUT) continue;
    #pragma unroll
    for (int m = 0; m < 4; ++m) {
      int ch0 = qb + (m << 4) + ((lane >> 4) << 2);
      f32x4 bb = *(const f32x4*)(b1 + ch0);
      ushort4 o;
      o.x = f2bf(fmaxf(acc[m][n][0] + bb[0], 0.f));
      o.y = f2bf(fmaxf(acc[m][n][1] + bb[1], 0.f));
      o.z = f2bf(fmaxf(acc[m][n][2] + bb[2], 0.f));
      o.w = f2bf(fmaxf(acc[m][n][3] + bb[3], 0.f));
      *(ushort4*)(h1 + ((long)b * T_OUT + t) * 512 + ch0) = o;
    }
  }
}

// post2 + log_softmax: M=256 (4 waves x 64q), K=512, out f32 [b][q][T_OUT]
__global__ __launch_bounds__(256) void k_post2sm(
    const u16* __restrict__ h1, const u16* __restrict__ Wp,
    const float* __restrict__ b2, float* __restrict__ out) {
  __shared__ float redM[4][64];
  __shared__ float redS[4][64];
  int lane = threadIdx.x & 63, wave = threadIdx.x >> 6;
  int b = blockIdx.z;
  int qb = wave << 6;
  int tb = blockIdx.x << 6;
  int lrow = lane & 15, lk = (lane >> 4) << 3;
  int mt0 = qb >> 4;
  f32x4 zed = {0.f, 0.f, 0.f, 0.f};
  f32x4 acc[4][4];
  #pragma unroll
  for (int m = 0; m < 4; ++m)
    #pragma unroll
    for (int n = 0; n < 4; ++n) acc[m][n] = zed;
  const u16* hb = h1 + (long)b * T_OUT * 512;
  for (int ks = 0; ks < 16; ++ks) {
    short8_t a[4];
    #pragma unroll
    for (int m = 0; m < 4; ++m)
      a[m] = *(const short8_t*)(Wp + ((long)((mt0 + m) * 16 + ks) << 9) + (lane << 3));
    #pragma unroll
    for (int n = 0; n < 4; ++n) {
      int row = tb + (n << 4) + lrow;
      row = min(row, T_OUT - 1);
      short8_t bv = *(const short8_t*)(hb + (long)row * 512 + (ks << 5) + lk);
      #pragma unroll
      for (int m = 0; m < 4; ++m)
        acc[m][n] = __builtin_amdgcn_mfma_f32_16x16x32_bf16(a[m], bv, acc[m][n], 0, 0, 0);
    }
  }
  #pragma unroll
  for (int m = 0; m < 4; ++m) {
    int q0 = qb + (m << 4) + ((lane >> 4) << 2);
    f32x4 bb = *(const f32x4*)(b2 + q0);
    #pragma unroll
    for (int n = 0; n < 4; ++n) acc[m][n] += bb;
  }
  float fm[4], fs[4];
  #pragma unroll
  for (int n = 0; n < 4; ++n) {
    float pm = -1e30f;
    #pragma unroll
    for (int m = 0; m < 4; ++m)
      #pragma unroll
      for (int r = 0; r < 4; ++r) pm = fmaxf(pm, acc[m][n][r]);
    pm = fmaxf(pm, __shfl_xor(pm, 16));
    pm = fmaxf(pm, __shfl_xor(pm, 32));
    if (lane < 16) redM[wave][(n << 4) + lane] = pm;
  }
  __syncthreads();
  #pragma unroll
  for (int n = 0; n < 4; ++n) {
    float mm = redM[0][(n << 4) + lrow];
    mm = fmaxf(mm, redM[1][(n << 4) + lrow]);
    mm = fmaxf(mm, redM[2][(n << 4) + lrow]);
    mm = fmaxf(mm, redM[3][(n << 4) + lrow]);
    fm[n] = mm;
    float ps = 0.f;
    #pragma unroll
    for (int m = 0; m < 4; ++m)
      #pragma unroll
      for (int r = 0; r < 4; ++r) ps += __expf(acc[m][n][r] - mm);
    ps += __shfl_xor(ps, 16);
    ps += __shfl_xor(ps, 32);
    if (lane < 16) redS[wave][(n << 4) + lane] = ps;
  }
  __syncthreads();
  #pragma unroll
  for (int n = 0; n < 4; ++n) {
    float ss = redS[0][(n << 4) + lrow] + redS[1][(n << 4) + lrow] +
               redS[2][(n << 4) + lrow] + redS[3][(n << 4) + lrow];
    fs[n] = fm[n] + logf(ss);
  }
  #pragma unroll
  for (int n = 0; n < 4; ++n) {
    int t = tb + (n << 4) + lrow;
    if (t >= T_OUT) continue;
    #pragma unroll
    for (int m = 0; m < 4; ++m) {
      int q0 = qb + (m << 4) + ((lane >> 4) << 2);
      #pragma unroll
      for (int r = 0; r < 4; ++r)
        out[((long)b * 256 + q0 + r) * T_OUT + t] = acc[m][n][r] - fs[n];
    }
  }
}

extern "C" void kernel_launch(void* const* d_in, const int* in_sizes, int n_in,
                              void* d_out, int out_size, void* d_ws, size_t ws_size,
                              hipStream_t stream) {
  const float* wav       = (const float*)d_in[0];
  const float* lc_sparse = (const float*)d_in[1];
  const float* lc_conv_w = (const float*)d_in[2];
  const float* lc_conv_b = (const float*)d_in[3];
  const float* ups_w[4]  = {(const float*)d_in[4], (const float*)d_in[6], (const float*)d_in[8], (const float*)d_in[10]};
  const float* ups_b[4]  = {(const float*)d_in[5], (const float*)d_in[7], (const float*)d_in[9], (const float*)d_in[11]};
  const float* emb_w     = (const float*)d_in[12];
  const float* emb_b     = (const float*)d_in[13];
  const float* base_w    = (const float*)d_in[14];
  const float* base_b    = (const float*)d_in[15];
  const float* sig_w     = (const float*)d_in[16];
  const float* sig_b     = (const float*)d_in[17];
  const float* gate_w    = (const float*)d_in[18];
  const float* gate_b    = (const float*)d_in[19];
  const float* psig_w    = (const float*)d_in[20];
  const float* pgate_w   = (const float*)d_in[21];
  const float* skp_w     = (const float*)d_in[22];
  const float* res_w     = (const float*)d_in[23];
  const float* post1_w   = (const float*)d_in[24];
  const float* post1_b   = (const float*)d_in[25];
  const float* post2_w   = (const float*)d_in[26];
  const float* post2_b   = (const float*)d_in[27];
  const int* spk         = (const int*)d_in[28];
  const int* jit         = (const int*)d_in[29];
  float* out = (float*)d_out;

  size_t off = 0;
  auto alloc = [&](size_t bytes) -> void* {
    off = (off + 255) & ~(size_t)255;
    void* p = (char*)d_ws + off;
    off += bytes;
    return p;
  };
  u16* wfgF   = (u16*)alloc(20L * 229376 * 2);
  u16* wfgG   = (u16*)alloc(20L * 229376 * 2);
  u16* wskpF  = (u16*)alloc(20L * 65536 * 2);
  u16* wresF  = (u16*)alloc(20L * 98304 * 2);
  u16* wbaseF = (u16*)alloc(384L * 256 * 2);
  u16* wp1F   = (u16*)alloc(512L * 256 * 2);
  u16* wp2F   = (u16*)alloc(256L * 512 * 2);
  float* wtc1 = (float*)alloc(5L * 640 * 128 * 4);
  float* wtc2 = (float*)alloc(4L * 512 * 128 * 4);
  float* wtc3 = (float*)alloc(4L * 512 * 128 * 4);
  u16* wtc4F  = (u16*)alloc(4L * 65536 * 2);
  float* cbias = (float*)alloc(20L * 2 * 4 * 256 * 4);
  float* gc    = (float*)alloc(4L * 128 * 4);
  u16* lcbf    = (u16*)alloc(4L * T_IN * 128 * 2);
  u16* xA      = (u16*)alloc(4L * T_IN * 384 * 2);
  u16* xB      = (u16*)alloc(4L * T_IN * 384 * 2);
  u16* zbuf    = (u16*)alloc(4L * T_IN * 256 * 2);
  float* skip  = (float*)alloc(4L * T_OUT * 256 * 4);
  // temporal aliases (stream-ordered, lifetimes disjoint):
  float* lcs0 = (float*)zbuf;
  float* lcs1 = lcs0 + 4L * 128 * 64;
  float* lcs2 = lcs1 + 4L * 128 * 290;
  float* lcs3 = lcs2 + 4L * 128 * 1148;
  u16* im3    = xB;
  u16* wavT   = (u16*)skip;
  u16* h1bf   = xA;
  (void)ws_size; (void)in_sizes; (void)n_in; (void)out_size;

  // weight packs
  k_pack_frag_gau<<<4480, 256, 0, stream>>>(sig_w, gate_w, psig_w, pgate_w, wfgF, wfgG);
  k_pack_frag<<<1280, 256, 0, stream>>>(skp_w, wskpF, 256, 256, 20, 256L * 256);
  k_pack_frag<<<1920, 256, 0, stream>>>(res_w, wresF, 384, 256, 20, 384L * 256);
  k_pack_frag<<<96, 256, 0, stream>>>(base_w, wbaseF, 384, 256, 1, 0);
  k_pack_frag<<<128, 256, 0, stream>>>(post1_w, wp1F, 512, 256, 1, 0);
  k_pack_frag<<<128, 256, 0, stream>>>(post2_w, wp2F, 256, 512, 1, 0);
  k_pack_tconv<<<320, 256, 0, stream>>>(ups_w[0], wtc1, 5, 25, 5);
  k_pack_tconv<<<256, 256, 0, stream>>>(ups_w[1], wtc2, 4, 16, 4);
  k_pack_tconv<<<256, 256, 0, stream>>>(ups_w[2], wtc3, 4, 16, 4);
  k_pack_tc4f<<<256, 256, 0, stream>>>(ups_w[3], wtc4F);
  k_gc<<<1, 512, 0, stream>>>(emb_w, emb_b, spk, gc);
  k_cbias<<<dim3(20, 8), 256, 0, stream>>>(psig_w, pgate_w, sig_b, gate_b, gc, cbias);

  // local-conditioning chain
  k_lc0<<<dim3(4, 62), 128, 0, stream>>>(lc_sparse, jit, lc_conv_w, lc_conv_b, lcs0);
  k_tconvg<5><<<dim3(1, 10, 4), 256, 0, stream>>>(lcs0, 62, 64, lcs1, 290, 290, wtc1, ups_b[0], 5);
  k_tconvg<4><<<dim3(5, 8, 4), 256, 0, stream>>>(lcs1, 290, 290, lcs2, 1148, 1148, wtc2, ups_b[1], 4);
  k_tconvg<4><<<dim3(18, 8, 4), 256, 0, stream>>>(lcs2, 1148, 1148, lcs3, 4580, 4580, wtc3, ups_b[2], 4);
  k_im2col3<<<2048, 256, 0, stream>>>(lcs3, im3);
  k_tconv4m<<<dim3(18, 8, 4), 256, 0, stream>>>(im3, wtc4F, ups_b[3], lcbf);

  // wav transpose + base 1x1 conv (MFMA) -> xA t-major bf16
  k_wav_t<<<dim3(287, 8, 4), 256, 0, stream>>>(wav, wavT);
  k_basem<<<dim3(72, 6, 4), 256, 0, stream>>>(wavT, wbaseF, base_b, xA);

  static const int DILS[20] = {1, 2, 4, 8, 16, 32, 64, 128, 256, 512,
                               1, 2, 4, 8, 16, 32, 64, 128, 256, 512};
  int cum = 0;
  u16* xc = xA; u16* xn = xB;
  for (int l = 0; l < 20; ++l) {
    int dd = DILS[l], lw = dd, cl = cum + lw;
    int Lz = T_IN - cl;
    int sl = 2046 - cl;
    int nt = (Lz + 63) / 64;
    int gx = 16 * ((nt + 7) >> 3);
    k_gau6<<<dim3(gx, 1, 4), 256, 0, stream>>>(
        xc, lcbf, wfgF + (long)l * 229376, wfgG + (long)l * 229376,
        cbias + (long)l * 2048, zbuf, Lz, dd, cl, nt);
    int nsl = (l == 19) ? 2 : 5;
    k_skipres6<<<dim3(nsl, nt, 4), 256, 0, stream>>>(
        zbuf, wskpF + (long)l * 65536, wresF + (long)l * 98304,
        xc, skip, xn, Lz, sl, lw, (l == 0) ? 1 : 0);
    cum = cl;
    u16* t = xc; xc = xn; xn = t;
  }

  k_post1<<<dim3(64, 8, 4), 256, 0, stream>>>(skip, wp1F, post1_b, h1bf);
  k_post2sm<<<dim3(255, 1, 4), 256, 0, stream>>>(h1bf, wp2F, post2_b, out);
}